// Round 1
// baseline (1262.498 us; speedup 1.0000x reference)
//
#include <hip/hip_runtime.h>
#include <hip/hip_bf16.h>

// Problem constants: B=4, T=2048, E=8, C=1024, I=2048. M = B*T = 8192.
// Outputs: agg [8192,1024] fp32, experts_out [8192,8,1024] fp32, concat in d_out.

typedef unsigned short u16;
typedef __bf16 v8bf __attribute__((ext_vector_type(8)));
typedef float  v4f  __attribute__((ext_vector_type(4)));

#define M_TOT 8192
#define E_DIM 8
#define C_DIM 1024
#define I_DIM 2048

__device__ inline u16 f2b(float f) {
    __hip_bfloat16 h = __float2bfloat16(f);
    return *reinterpret_cast<u16*>(&h);
}

// async global->LDS, 16B per lane; LDS dest = wave-uniform base + lane*16
__device__ inline void gload16(const u16* g, u16* l) {
    __builtin_amdgcn_global_load_lds(
        (const __attribute__((address_space(1))) void*)g,
        (__attribute__((address_space(3))) void*)l,
        16, 0, 0);
}

// ---------------- pass 0: conversions ----------------

__global__ __launch_bounds__(256) void cvt_x_kernel(const float* __restrict__ x,
                                                    u16* __restrict__ xb) {
    int idx = blockIdx.x * 256 + threadIdx.x;   // each thread: 4 floats
    float4 v = reinterpret_cast<const float4*>(x)[idx];
    ushort4 o;
    o.x = f2b(v.x); o.y = f2b(v.y); o.z = f2b(v.z); o.w = f2b(v.w);
    reinterpret_cast<ushort4*>(xb)[idx] = o;
}

// in: (E, R, Cd) fp32 row-major  ->  out: (E, Cd, R) bf16
__global__ __launch_bounds__(256) void transpose_cvt_kernel(const float* __restrict__ in,
                                                            u16* __restrict__ out,
                                                            int R, int Cd) {
    __shared__ float tile[32][33];
    int e = blockIdx.z;
    const float* ip = in + (size_t)e * R * Cd;
    u16* op = out + (size_t)e * R * Cd;
    int c0 = blockIdx.x * 32, r0 = blockIdx.y * 32;
    int tx = threadIdx.x & 31;
    int ty = threadIdx.x >> 5;   // 0..7
#pragma unroll
    for (int k = 0; k < 4; k++)
        tile[ty + 8 * k][tx] = ip[(size_t)(r0 + ty + 8 * k) * Cd + c0 + tx];
    __syncthreads();
#pragma unroll
    for (int k = 0; k < 4; k++)
        op[(size_t)(c0 + ty + 8 * k) * R + r0 + tx] = f2b(tile[tx][ty + 8 * k]);
}

// ---------------- GEMM1: h = gelu(x @ w1[e]), bf16 out ----------------
// A: M_TOT x 1024 bf16 (k-contig). Bt: 2048(N=i) x 1024(K=c) bf16 (k-contig).
// H: M_TOT x 2048 bf16.
__global__ __launch_bounds__(256, 2) void gemm1_kernel(const u16* __restrict__ A,
                                                       const u16* __restrict__ Bt,
                                                       u16* __restrict__ H) {
    const int K = 1024;
    __shared__ __align__(16) u16 As[128 * 32];
    __shared__ __align__(16) u16 Bs[128 * 32];
    int t = threadIdx.x, w = t >> 6, l = t & 63;
    int m0 = blockIdx.y * 128, n0 = blockIdx.x * 128;
    int wm = w >> 1, wn = w & 1;

    const u16* ag = A  + (size_t)(m0 + w * 16 + (l >> 2)) * K + (l & 3) * 8;
    const u16* bg = Bt + (size_t)(n0 + w * 16 + (l >> 2)) * K + (l & 3) * 8;
    u16* asl = As + w * 512;
    u16* bsl = Bs + w * 512;
    const u16* afp = As + (size_t)(64 * wm + (l & 15)) * 32 + (l >> 4) * 8;
    const u16* bfp = Bs + (size_t)(64 * wn + (l & 15)) * 32 + (l >> 4) * 8;

    v4f acc[4][4];
#pragma unroll
    for (int i = 0; i < 4; i++)
#pragma unroll
        for (int j = 0; j < 4; j++) acc[i][j] = (v4f){0.f, 0.f, 0.f, 0.f};

    for (int k0 = 0; k0 < K; k0 += 32) {
        gload16(ag + k0, asl);
        gload16(ag + (size_t)64 * K + k0, asl + 2048);
        gload16(bg + k0, bsl);
        gload16(bg + (size_t)64 * K + k0, bsl + 2048);
        __syncthreads();   // compiler emits vmcnt(0) drain before barrier
        v8bf af[4], bf[4];
#pragma unroll
        for (int i = 0; i < 4; i++) af[i] = *(const v8bf*)(afp + i * 16 * 32);
#pragma unroll
        for (int j = 0; j < 4; j++) bf[j] = *(const v8bf*)(bfp + j * 16 * 32);
#pragma unroll
        for (int i = 0; i < 4; i++)
#pragma unroll
            for (int j = 0; j < 4; j++)
                acc[i][j] = __builtin_amdgcn_mfma_f32_16x16x32_bf16(af[i], bf[j], acc[i][j], 0, 0, 0);
        __syncthreads();
    }

    int lr = (l >> 4) << 2;   // C/D: row = (lane>>4)*4 + reg, col = lane&15
    int lc = l & 15;
#pragma unroll
    for (int i = 0; i < 4; i++) {
        int mg = m0 + 64 * wm + 16 * i + lr;
#pragma unroll
        for (int j = 0; j < 4; j++) {
            int ng = n0 + 64 * wn + 16 * j + lc;
#pragma unroll
            for (int r = 0; r < 4; r++) {
                float v = acc[i][j][r];
                float g = 0.5f * v * (1.0f + erff(v * 0.70710678118654752f));
                H[(size_t)(mg + r) * 2048 + ng] = f2b(g);
            }
        }
    }
}

// ---------------- GEMM2: eo[:,e,:] = h @ w2[e], fp32 strided out ----------------
// A: M_TOT x 2048 bf16 (h). Bt: 1024(N=c) x 2048(K=i) bf16. EO: [m][E][c] fp32.
__global__ __launch_bounds__(256, 2) void gemm2_kernel(const u16* __restrict__ A,
                                                       const u16* __restrict__ Bt,
                                                       float* __restrict__ EO,
                                                       int e) {
    const int K = 2048;
    __shared__ __align__(16) u16 As[128 * 32];
    __shared__ __align__(16) u16 Bs[128 * 32];
    int t = threadIdx.x, w = t >> 6, l = t & 63;
    int m0 = blockIdx.y * 128, n0 = blockIdx.x * 128;
    int wm = w >> 1, wn = w & 1;

    const u16* ag = A  + (size_t)(m0 + w * 16 + (l >> 2)) * K + (l & 3) * 8;
    const u16* bg = Bt + (size_t)(n0 + w * 16 + (l >> 2)) * K + (l & 3) * 8;
    u16* asl = As + w * 512;
    u16* bsl = Bs + w * 512;
    const u16* afp = As + (size_t)(64 * wm + (l & 15)) * 32 + (l >> 4) * 8;
    const u16* bfp = Bs + (size_t)(64 * wn + (l & 15)) * 32 + (l >> 4) * 8;

    v4f acc[4][4];
#pragma unroll
    for (int i = 0; i < 4; i++)
#pragma unroll
        for (int j = 0; j < 4; j++) acc[i][j] = (v4f){0.f, 0.f, 0.f, 0.f};

    for (int k0 = 0; k0 < K; k0 += 32) {
        gload16(ag + k0, asl);
        gload16(ag + (size_t)64 * K + k0, asl + 2048);
        gload16(bg + k0, bsl);
        gload16(bg + (size_t)64 * K + k0, bsl + 2048);
        __syncthreads();
        v8bf af[4], bf[4];
#pragma unroll
        for (int i = 0; i < 4; i++) af[i] = *(const v8bf*)(afp + i * 16 * 32);
#pragma unroll
        for (int j = 0; j < 4; j++) bf[j] = *(const v8bf*)(bfp + j * 16 * 32);
#pragma unroll
        for (int i = 0; i < 4; i++)
#pragma unroll
            for (int j = 0; j < 4; j++)
                acc[i][j] = __builtin_amdgcn_mfma_f32_16x16x32_bf16(af[i], bf[j], acc[i][j], 0, 0, 0);
        __syncthreads();
    }

    int lr = (l >> 4) << 2;
    int lc = l & 15;
#pragma unroll
    for (int i = 0; i < 4; i++) {
        int mg = m0 + 64 * wm + 16 * i + lr;
#pragma unroll
        for (int j = 0; j < 4; j++) {
            int ng = n0 + 64 * wn + 16 * j + lc;
#pragma unroll
            for (int r = 0; r < 4; r++) {
                EO[((size_t)(mg + r) * E_DIM + e) * C_DIM + ng] = acc[i][j][r];
            }
        }
    }
}

// ---------------- combine: agg[m][c] = sum_e r[m][e] * eo[m][e][c] ----------------
__global__ __launch_bounds__(256) void combine_kernel(const float* __restrict__ EO,
                                                      const float* __restrict__ Rw,
                                                      float* __restrict__ agg) {
    int idx = blockIdx.x * 256 + threadIdx.x;   // M_TOT * 256 threads
    int m = idx >> 8, cq = idx & 255;           // 256 float4 per row
    const float4* eo4 = reinterpret_cast<const float4*>(EO);
    float4 s = make_float4(0.f, 0.f, 0.f, 0.f);
#pragma unroll
    for (int e = 0; e < E_DIM; e++) {
        float r = Rw[m * E_DIM + e];
        float4 v = eo4[((size_t)m * E_DIM + e) * 256 + cq];
        s.x += r * v.x; s.y += r * v.y; s.z += r * v.z; s.w += r * v.w;
    }
    reinterpret_cast<float4*>(agg)[(size_t)m * 256 + cq] = s;
}

extern "C" void kernel_launch(void* const* d_in, const int* in_sizes, int n_in,
                              void* d_out, int out_size, void* d_ws, size_t ws_size,
                              hipStream_t stream) {
    const float* x  = (const float*)d_in[0];
    const float* rw = (const float*)d_in[1];
    const float* w1 = (const float*)d_in[2];
    const float* w2 = (const float*)d_in[3];

    float* agg = (float*)d_out;
    float* EO  = agg + (size_t)M_TOT * C_DIM;   // experts_out region

    // workspace layout (bf16), total 112 MiB
    u16* xb  = (u16*)d_ws;                              // 8192*1024
    u16* w1T = xb  + (size_t)M_TOT * C_DIM;             // 8*2048*1024  [e][i][c]
    u16* w2T = w1T + (size_t)E_DIM * I_DIM * C_DIM;     // 8*1024*2048  [e][c][i]
    u16* h   = w2T + (size_t)E_DIM * C_DIM * I_DIM;     // 8192*2048 (reused per expert)

    cvt_x_kernel<<<(M_TOT * C_DIM) / 1024, 256, 0, stream>>>(x, xb);
    transpose_cvt_kernel<<<dim3(I_DIM / 32, C_DIM / 32, E_DIM), 256, 0, stream>>>(w1, w1T, C_DIM, I_DIM);
    transpose_cvt_kernel<<<dim3(C_DIM / 32, I_DIM / 32, E_DIM), 256, 0, stream>>>(w2, w2T, I_DIM, C_DIM);

    for (int e = 0; e < E_DIM; e++) {
        gemm1_kernel<<<dim3(I_DIM / 128, M_TOT / 128), 256, 0, stream>>>(
            xb, w1T + (size_t)e * I_DIM * C_DIM, h);
        gemm2_kernel<<<dim3(C_DIM / 128, M_TOT / 128), 256, 0, stream>>>(
            h, w2T + (size_t)e * C_DIM * I_DIM, EO, e);
    }

    combine_kernel<<<M_TOT, 256, 0, stream>>>(EO, rw, agg);
}

// Round 2
// 1137.227 us; speedup vs baseline: 1.1102x; 1.1102x over previous
//
#include <hip/hip_runtime.h>
#include <hip/hip_bf16.h>

// Problem constants: B=4, T=2048, E=8, C=1024, I=2048. M = B*T = 8192.
// Outputs: agg [8192,1024] fp32, experts_out [8192,8,1024] fp32, concat in d_out.

typedef unsigned short u16;
typedef __bf16 v8bf __attribute__((ext_vector_type(8)));
typedef float  v4f  __attribute__((ext_vector_type(4)));

#define M_TOT 8192
#define E_DIM 8
#define C_DIM 1024
#define I_DIM 2048

__device__ inline u16 f2b(float f) {
    __hip_bfloat16 h = __float2bfloat16(f);
    return *reinterpret_cast<u16*>(&h);
}

// tanh-form GELU: max |diff vs exact-erf gelu| ~3e-3, NaN-safe at |x| large.
// tanh(z) = 1 - 2/(1+e^{2z}); z = 0.79788456x(1+0.044715x^2)
__device__ inline float fast_gelu(float x) {
    float x2 = x * x;
    float z  = x * fmaf(0.0356774081f, x2, 0.7978845608f);
    float u  = __expf(2.0f * z);                     // v_exp_f32 path
    float th = fmaf(-2.0f, __builtin_amdgcn_rcpf(u + 1.0f), 1.0f);
    return 0.5f * x * (1.0f + th);
}

// async global->LDS, 16B per lane; LDS dest = wave-uniform base + lane*16
__device__ inline void gload16(const u16* g, u16* l) {
    __builtin_amdgcn_global_load_lds(
        (const __attribute__((address_space(1))) void*)g,
        (__attribute__((address_space(3))) void*)l,
        16, 0, 0);
}

// ---------------- pass 0: conversions ----------------

__global__ __launch_bounds__(256) void cvt_x_kernel(const float* __restrict__ x,
                                                    u16* __restrict__ xb) {
    int idx = blockIdx.x * 256 + threadIdx.x;   // each thread: 4 floats
    float4 v = reinterpret_cast<const float4*>(x)[idx];
    ushort4 o;
    o.x = f2b(v.x); o.y = f2b(v.y); o.z = f2b(v.z); o.w = f2b(v.w);
    reinterpret_cast<ushort4*>(xb)[idx] = o;
}

// in: (E, R, Cd) fp32 row-major  ->  out: (E, Cd, R) bf16
__global__ __launch_bounds__(256) void transpose_cvt_kernel(const float* __restrict__ in,
                                                            u16* __restrict__ out,
                                                            int R, int Cd) {
    __shared__ float tile[32][33];
    int e = blockIdx.z;
    const float* ip = in + (size_t)e * R * Cd;
    u16* op = out + (size_t)e * R * Cd;
    int c0 = blockIdx.x * 32, r0 = blockIdx.y * 32;
    int tx = threadIdx.x & 31;
    int ty = threadIdx.x >> 5;   // 0..7
#pragma unroll
    for (int k = 0; k < 4; k++)
        tile[ty + 8 * k][tx] = ip[(size_t)(r0 + ty + 8 * k) * Cd + c0 + tx];
    __syncthreads();
#pragma unroll
    for (int k = 0; k < 4; k++)
        op[(size_t)(c0 + ty + 8 * k) * R + r0 + tx] = f2b(tile[tx][ty + 8 * k]);
}

// ---------------- GEMM1: h[e] = gelu(x @ w1[e]), bf16 out ----------------
// A: M_TOT x 1024 bf16 (k-contig). w1T: [e] 2048(N=i) x 1024(K=c) bf16.
// H: per-expert M_TOT x 2048 bf16 at stride h_stride (0 in fallback mode).
__global__ __launch_bounds__(256, 2) void gemm1_kernel(const u16* __restrict__ A,
                                                       const u16* __restrict__ w1T,
                                                       u16* __restrict__ H,
                                                       int e_base, size_t h_stride) {
    const int K = 1024;
    int e = e_base + blockIdx.z;
    const u16* Bt = w1T + (size_t)e * I_DIM * C_DIM;
    u16* Hp = H + (size_t)blockIdx.z * h_stride;

    __shared__ __align__(16) u16 As[128 * 32];
    __shared__ __align__(16) u16 Bs[128 * 32];
    int t = threadIdx.x, w = t >> 6, l = t & 63;
    int m0 = blockIdx.y * 128, n0 = blockIdx.x * 128;
    int wm = w >> 1, wn = w & 1;

    const u16* ag = A  + (size_t)(m0 + w * 16 + (l >> 2)) * K + (l & 3) * 8;
    const u16* bg = Bt + (size_t)(n0 + w * 16 + (l >> 2)) * K + (l & 3) * 8;
    u16* asl = As + w * 512;
    u16* bsl = Bs + w * 512;
    const u16* afp = As + (size_t)(64 * wm + (l & 15)) * 32 + (l >> 4) * 8;
    const u16* bfp = Bs + (size_t)(64 * wn + (l & 15)) * 32 + (l >> 4) * 8;

    v4f acc[4][4];
#pragma unroll
    for (int i = 0; i < 4; i++)
#pragma unroll
        for (int j = 0; j < 4; j++) acc[i][j] = (v4f){0.f, 0.f, 0.f, 0.f};

    for (int k0 = 0; k0 < K; k0 += 32) {
        gload16(ag + k0, asl);
        gload16(ag + (size_t)64 * K + k0, asl + 2048);
        gload16(bg + k0, bsl);
        gload16(bg + (size_t)64 * K + k0, bsl + 2048);
        __syncthreads();
        v8bf af[4], bf[4];
#pragma unroll
        for (int i = 0; i < 4; i++) af[i] = *(const v8bf*)(afp + i * 16 * 32);
#pragma unroll
        for (int j = 0; j < 4; j++) bf[j] = *(const v8bf*)(bfp + j * 16 * 32);
#pragma unroll
        for (int i = 0; i < 4; i++)
#pragma unroll
            for (int j = 0; j < 4; j++)
                acc[i][j] = __builtin_amdgcn_mfma_f32_16x16x32_bf16(af[i], bf[j], acc[i][j], 0, 0, 0);
        __syncthreads();
    }

    int lr = (l >> 4) << 2;   // C/D: row = (lane>>4)*4 + reg, col = lane&15
    int lc = l & 15;
#pragma unroll
    for (int i = 0; i < 4; i++) {
        int mg = m0 + 64 * wm + 16 * i + lr;
#pragma unroll
        for (int j = 0; j < 4; j++) {
            int ng = n0 + 64 * wn + 16 * j + lc;
#pragma unroll
            for (int r = 0; r < 4; r++) {
                Hp[(size_t)(mg + r) * 2048 + ng] = f2b(fast_gelu(acc[i][j][r]));
            }
        }
    }
}

// ---------------- GEMM2: eo[:,e,:] = h[e] @ w2[e], fp32 strided out ----------------
// H: per-expert M_TOT x 2048 bf16 at stride h_stride. w2T: [e] 1024(N=c) x 2048(K=i).
// EO: [m][E][c] fp32.
__global__ __launch_bounds__(256, 2) void gemm2_kernel(const u16* __restrict__ H,
                                                       const u16* __restrict__ w2T,
                                                       float* __restrict__ EO,
                                                       int e_base, size_t h_stride) {
    const int K = 2048;
    int e = e_base + blockIdx.z;
    const u16* A  = H + (size_t)blockIdx.z * h_stride;
    const u16* Bt = w2T + (size_t)e * C_DIM * I_DIM;

    __shared__ __align__(16) u16 As[128 * 32];
    __shared__ __align__(16) u16 Bs[128 * 32];
    int t = threadIdx.x, w = t >> 6, l = t & 63;
    int m0 = blockIdx.y * 128, n0 = blockIdx.x * 128;
    int wm = w >> 1, wn = w & 1;

    const u16* ag = A  + (size_t)(m0 + w * 16 + (l >> 2)) * K + (l & 3) * 8;
    const u16* bg = Bt + (size_t)(n0 + w * 16 + (l >> 2)) * K + (l & 3) * 8;
    u16* asl = As + w * 512;
    u16* bsl = Bs + w * 512;
    const u16* afp = As + (size_t)(64 * wm + (l & 15)) * 32 + (l >> 4) * 8;
    const u16* bfp = Bs + (size_t)(64 * wn + (l & 15)) * 32 + (l >> 4) * 8;

    v4f acc[4][4];
#pragma unroll
    for (int i = 0; i < 4; i++)
#pragma unroll
        for (int j = 0; j < 4; j++) acc[i][j] = (v4f){0.f, 0.f, 0.f, 0.f};

    for (int k0 = 0; k0 < K; k0 += 32) {
        gload16(ag + k0, asl);
        gload16(ag + (size_t)64 * K + k0, asl + 2048);
        gload16(bg + k0, bsl);
        gload16(bg + (size_t)64 * K + k0, bsl + 2048);
        __syncthreads();
        v8bf af[4], bf[4];
#pragma unroll
        for (int i = 0; i < 4; i++) af[i] = *(const v8bf*)(afp + i * 16 * 32);
#pragma unroll
        for (int j = 0; j < 4; j++) bf[j] = *(const v8bf*)(bfp + j * 16 * 32);
#pragma unroll
        for (int i = 0; i < 4; i++)
#pragma unroll
            for (int j = 0; j < 4; j++)
                acc[i][j] = __builtin_amdgcn_mfma_f32_16x16x32_bf16(af[i], bf[j], acc[i][j], 0, 0, 0);
        __syncthreads();
    }

    int lr = (l >> 4) << 2;
    int lc = l & 15;
#pragma unroll
    for (int i = 0; i < 4; i++) {
        int mg = m0 + 64 * wm + 16 * i + lr;
#pragma unroll
        for (int j = 0; j < 4; j++) {
            int ng = n0 + 64 * wn + 16 * j + lc;
#pragma unroll
            for (int r = 0; r < 4; r++) {
                EO[((size_t)(mg + r) * E_DIM + e) * C_DIM + ng] = acc[i][j][r];
            }
        }
    }
}

// ---------------- combine: agg[m][c] = sum_e r[m][e] * eo[m][e][c] ----------------
__global__ __launch_bounds__(256) void combine_kernel(const float* __restrict__ EO,
                                                      const float* __restrict__ Rw,
                                                      float* __restrict__ agg) {
    int idx = blockIdx.x * 256 + threadIdx.x;
    int m = idx >> 8, cq = idx & 255;           // 256 float4 per row
    const float4* eo4 = reinterpret_cast<const float4*>(EO);
    float4 s = make_float4(0.f, 0.f, 0.f, 0.f);
#pragma unroll
    for (int e = 0; e < E_DIM; e++) {
        float r = Rw[m * E_DIM + e];
        float4 v = eo4[((size_t)m * E_DIM + e) * 256 + cq];
        s.x += r * v.x; s.y += r * v.y; s.z += r * v.z; s.w += r * v.w;
    }
    reinterpret_cast<float4*>(agg)[(size_t)m * 256 + cq] = s;
}

extern "C" void kernel_launch(void* const* d_in, const int* in_sizes, int n_in,
                              void* d_out, int out_size, void* d_ws, size_t ws_size,
                              hipStream_t stream) {
    const float* x  = (const float*)d_in[0];
    const float* rw = (const float*)d_in[1];
    const float* w1 = (const float*)d_in[2];
    const float* w2 = (const float*)d_in[3];

    float* agg = (float*)d_out;
    float* EO  = agg + (size_t)M_TOT * C_DIM;   // experts_out region

    // workspace layout (bf16 elements)
    u16* xb  = (u16*)d_ws;                              // 8192*1024
    u16* w1T = xb  + (size_t)M_TOT * C_DIM;             // 8*2048*1024  [e][i][c]
    u16* w2T = w1T + (size_t)E_DIM * I_DIM * C_DIM;     // 8*1024*2048  [e][c][i]
    u16* h   = w2T + (size_t)E_DIM * C_DIM * I_DIM;     // h region

    size_t elems_before_h = (size_t)M_TOT * C_DIM + 2 * (size_t)E_DIM * I_DIM * C_DIM;
    size_t h_per_expert   = (size_t)M_TOT * I_DIM;
    bool batched = ws_size >= (elems_before_h + (size_t)E_DIM * h_per_expert) * sizeof(u16);

    cvt_x_kernel<<<(M_TOT * C_DIM) / 1024, 256, 0, stream>>>(x, xb);
    transpose_cvt_kernel<<<dim3(I_DIM / 32, C_DIM / 32, E_DIM), 256, 0, stream>>>(w1, w1T, C_DIM, I_DIM);
    transpose_cvt_kernel<<<dim3(C_DIM / 32, I_DIM / 32, E_DIM), 256, 0, stream>>>(w2, w2T, I_DIM, C_DIM);

    if (batched) {
        gemm1_kernel<<<dim3(I_DIM / 128, M_TOT / 128, E_DIM), 256, 0, stream>>>(
            xb, w1T, h, 0, h_per_expert);
        gemm2_kernel<<<dim3(C_DIM / 128, M_TOT / 128, E_DIM), 256, 0, stream>>>(
            h, w2T, EO, 0, h_per_expert);
    } else {
        for (int e = 0; e < E_DIM; e++) {
            gemm1_kernel<<<dim3(I_DIM / 128, M_TOT / 128, 1), 256, 0, stream>>>(
                xb, w1T, h, e, 0);
            gemm2_kernel<<<dim3(C_DIM / 128, M_TOT / 128, 1), 256, 0, stream>>>(
                h, w2T, EO, e, 0);
        }
    }

    combine_kernel<<<M_TOT, 256, 0, stream>>>(EO, rw, agg);
}